// Round 6
// baseline (321.479 us; speedup 1.0000x reference)
//
#include <hip/hip_runtime.h>

// Problem: B=256, N=8192, K=16, fp32.
// out[b,n,k] = min(y[n], 0.5*(y[n-1]+y[n+1])) - param   (interior n)
//            = y[n] - param                              (n==0 or n==N-1)
// where y = x + param. Pure memory-bound 3-point stencil along N.
//
// V6: pure-stream stencil — copy-identical dependency structure.
// Every prior version (LDS tile / wave-LDS / shfl pipeline) had a
// cross-lane exchange + wait between load and store. Here each lane loads
// its three stencil inputs DIRECTLY via three overlapping wave-contiguous
// 1KB loads shifted by -64B / 0 / +64B. The shifted loads re-touch lines
// already in L1 (footprint ~3KB/step vs 32KB L1), so HBM traffic is
// unchanged; per tile-step the kernel is 6 independent loads -> register
// math -> 1 store. No LDS, no barriers, no shfl. Persistent waves (2048
// blocks), each sweeping a contiguous 256-row span in 16-row steps.

#define B_    256
#define N_    8192
#define KQ    4                        // float4 per n-row (K=16 floats)
#define TPB   256
#define GRID  2048
#define WPB   (TPB / 64)               // 4 waves per block
#define NWAVES (GRID * WPB)            // 8192 waves
#define WAVES_PER_B (NWAVES / B_)      // 32 waves per batch
#define SPAN  (N_ / WAVES_PER_B)       // 256 rows per wave
#define NSTEP (SPAN / 16)              // 16 tile-steps per wave

static_assert(NWAVES % B_ == 0, "wave/batch split");
static_assert(N_ % WAVES_PER_B == 0, "span split");

__global__ __launch_bounds__(TPB)
void convex_kernel(const float4* __restrict__ x4,
                   const float4* __restrict__ p4,
                   float4* __restrict__ o4)
{
    const int tid = threadIdx.x;
    const int w   = tid >> 6;
    const int l   = tid & 63;              // lane: f4 offset within 1KB tile
    const int g   = l >> 2;                // n-row within 16-row tile
    const int wid = blockIdx.x * WPB + w;  // 0..8191
    const int b   = wid >> 5;              // batch  (32 waves per batch)
    const int s   = (wid & 31) * SPAN;     // first row of this wave's span

    // float4 index of this lane in tile-step 0; max ~2^23 so int is fine.
    int idx = (b * N_ + s) * KQ + l;

#pragma unroll 2
    for (int i = 0; i < NSTEP; ++i, idx += 16 * KQ) {
        const int n  = s + i * 16 + g;     // row within batch
        const bool e0 = (n == 0);
        const bool e1 = (n == N_ - 1);
        // neighbor-row addresses: whole-wave contiguous spans shifted by
        // -/+64B; clamped at batch edges (clamped values never consumed:
        // edge rows take the y-param path below).
        const int ia = e0 ? idx : idx - KQ;
        const int id = e1 ? idx : idx + KQ;

        // 6 independent loads, all issued before any use.
        const float4 xc = x4[idx];
        const float4 pc = p4[idx];
        const float4 xa = x4[ia];
        const float4 pa = p4[ia];
        const float4 xd = x4[id];
        const float4 pd = p4[id];

        const float4 yc = make_float4(xc.x + pc.x, xc.y + pc.y,
                                      xc.z + pc.z, xc.w + pc.w);
        const float4 ya = make_float4(xa.x + pa.x, xa.y + pa.y,
                                      xa.z + pa.z, xa.w + pa.w);
        const float4 yd = make_float4(xd.x + pd.x, xd.y + pd.y,
                                      xd.z + pd.z, xd.w + pd.w);

        const bool edge = e0 | e1;
        float4 r;
        {
            const float mx = 0.5f * (ya.x + yd.x);
            const float my = 0.5f * (ya.y + yd.y);
            const float mz = 0.5f * (ya.z + yd.z);
            const float mw = 0.5f * (ya.w + yd.w);
            r.x = (edge ? yc.x : fminf(yc.x, mx)) - pc.x;
            r.y = (edge ? yc.y : fminf(yc.y, my)) - pc.y;
            r.z = (edge ? yc.z : fminf(yc.z, mz)) - pc.z;
            r.w = (edge ? yc.w : fminf(yc.w, mw)) - pc.w;
        }
        o4[idx] = r;
    }
}

extern "C" void kernel_launch(void* const* d_in, const int* in_sizes, int n_in,
                              void* d_out, int out_size, void* d_ws, size_t ws_size,
                              hipStream_t stream)
{
    const float4* x = (const float4*)d_in[0];
    const float4* p = (const float4*)d_in[1];
    float4*       o = (float4*)d_out;

    dim3 grid(GRID);     // 2048 blocks = 8192 waves, persistent sweep
    dim3 block(TPB);
    convex_kernel<<<grid, block, 0, stream>>>(x, p, o);
}

// Round 7
// 292.724 us; speedup vs baseline: 1.0982x; 1.0982x over previous
//
#include <hip/hip_runtime.h>

// Problem: B=256, N=8192, K=16, fp32.
// out[b,n,k] = min(y[n], 0.5*(y[n-1]+y[n+1])) - param   (interior n)
//            = y[n] - param                              (n==0 or n==N-1)
// where y = x + param. Pure memory-bound 3-point stencil along N.
//
// V7 = V1 (measured best, 105.6 us) + ONE change: NON-TEMPORAL LOADS on the
// input streams (plain stores — V5 showed nt stores regress).
// Theory: 402 MB working set vs 256 MB LLC puts reads in a ~50% L3-hit /
// 50% HBM-miss mixed regime at only 3.8 TB/s app BW, while pure-HBM
// streams (copy ubench) hit 6.3 TB/s. Across V1-V6, higher FETCH_SIZE
// correlates with LOWER time -> L3 partial service is hurting, not helping.
// nt loads stream inputs without LLC allocation, converting the read side
// to the pure-HBM regime.

#define B_    256
#define N_    8192
#define K_    16
#define TILE  64          // n-rows per block
#define KQ    4           // K/4 float4 columns per row
#define NTILES (N_ / TILE) // 128

typedef float nfloat4 __attribute__((ext_vector_type(4)));

__device__ __forceinline__ float4 nt_load(const float4* p) {
    nfloat4 v = __builtin_nontemporal_load(reinterpret_cast<const nfloat4*>(p));
    return make_float4(v.x, v.y, v.z, v.w);
}

__global__ __launch_bounds__(256)
void convex_kernel(const float4* __restrict__ x4,
                   const float4* __restrict__ p4,
                   float4* __restrict__ o4)
{
    // y-tile with 1-row halo on each side: 66 rows x 4 float4 = 4224 B LDS
    __shared__ float4 ysh[TILE + 2][KQ];

    const int tid = threadIdx.x;
    const int row = tid >> 2;     // 0..63 : n-row within tile
    const int col = tid & 3;      // 0..3  : float4 column within K
    const int blk = blockIdx.x;
    const int t   = blk & (NTILES - 1);  // tile index along N
    const int b   = blk >> 7;            // batch (NTILES == 128)
    const int n0  = t * TILE;

    const long base = ((long)b * N_ + n0) * KQ;   // float4 index of tile origin
    const long idx  = base + (long)row * KQ + col;

    // Main load: each element of x/param read exactly once.
    float4 xv = nt_load(&x4[idx]);
    float4 pv = nt_load(&p4[idx]);
    float4 yv = make_float4(xv.x + pv.x, xv.y + pv.y, xv.z + pv.z, xv.w + pv.w);
    ysh[row + 1][col] = yv;

    // Halo rows: n0-1 (lanes 0..3) and n0+TILE (lanes 4..7), guarded at the
    // array ends (those values are never consumed there: boundary rows take
    // the y-param path).
    if (tid < 8) {
        const int c = tid & 3;
        float4 h = make_float4(0.f, 0.f, 0.f, 0.f);
        if (tid < 4) {
            if (n0 > 0) {
                float4 hx = nt_load(&x4[base - KQ + c]);
                float4 hp = nt_load(&p4[base - KQ + c]);
                h = make_float4(hx.x + hp.x, hx.y + hp.y, hx.z + hp.z, hx.w + hp.w);
            }
            ysh[0][c] = h;
        } else {
            if (n0 + TILE < N_) {
                float4 hx = nt_load(&x4[base + (long)TILE * KQ + c]);
                float4 hp = nt_load(&p4[base + (long)TILE * KQ + c]);
                h = make_float4(hx.x + hp.x, hx.y + hp.y, hx.z + hp.z, hx.w + hp.w);
            }
            ysh[TILE + 1][c] = h;
        }
    }
    __syncthreads();

    const int n = n0 + row;
    float4 r;
    if (n == 0 || n == N_ - 1) {
        // Dy padded to 0 at the ends -> out = y - param
        r = make_float4(yv.x - pv.x, yv.y - pv.y, yv.z - pv.z, yv.w - pv.w);
    } else {
        float4 a = ysh[row][col];      // y[n-1]
        float4 d = ysh[row + 2][col];  // y[n+1]
        float4 m = make_float4(0.5f * (a.x + d.x), 0.5f * (a.y + d.y),
                               0.5f * (a.z + d.z), 0.5f * (a.w + d.w));
        r = make_float4(fminf(yv.x, m.x) - pv.x,
                        fminf(yv.y, m.y) - pv.y,
                        fminf(yv.z, m.z) - pv.z,
                        fminf(yv.w, m.w) - pv.w);
    }
    o4[idx] = r;
}

extern "C" void kernel_launch(void* const* d_in, const int* in_sizes, int n_in,
                              void* d_out, int out_size, void* d_ws, size_t ws_size,
                              hipStream_t stream)
{
    const float4* x = (const float4*)d_in[0];
    const float4* p = (const float4*)d_in[1];
    float4*       o = (float4*)d_out;

    dim3 grid(B_ * NTILES);   // 32768 blocks
    dim3 block(256);
    convex_kernel<<<grid, block, 0, stream>>>(x, p, o);
}